// Round 7
// baseline (2198.974 us; speedup 1.0000x reference)
//
#include <hip/hip_runtime.h>
#include <stdint.h>

typedef unsigned int u32;
typedef short short8 __attribute__((ext_vector_type(8)));
typedef short bf16x8 __attribute__((ext_vector_type(8)));
typedef float f32x4  __attribute__((ext_vector_type(4)));

#define B_ROWS 8192
#define HID    1024
#define KDIM   3072
#define NGATE  5

// GEMM tile: 256 batch rows x (5 gates x 64 hidden) per block, 8 waves 2Mx4N,
// per-wave output 128x80 (8 M-frags x 5 N-frags; N-frag == gate index).
// BK=32 -> 72 KiB double-buffered LDS -> 2 blocks/CU -> 4 waves/SIMD.
#define BM 256
#define BN 320
#define BK 32
#define NT (KDIM / BK)               // 96
#define LDSA_SH (BM * BK)            // 8192 shorts (16 KiB)
#define LDSB_SH (BN * BK)            // 10240 shorts (20 KiB)
#define BUF_SH  (LDSA_SH + LDSB_SH)  // 18432 shorts = 36 KiB
#define BUF_BYTES (BUF_SH * 2)       // 36864

// ---------- helpers ----------
__device__ __forceinline__ short f2bf(float f) {
  u32 u = __builtin_bit_cast(u32, f);
  u += 0x7FFFu + ((u >> 16) & 1u);   // round-to-nearest-even
  return (short)(u >> 16);
}

__device__ __forceinline__ float sigf(float v) { return 1.0f / (1.0f + __expf(-v)); }

__device__ __forceinline__ void async_copy16(const void* g, void* l) {
  __builtin_amdgcn_global_load_lds(
      (__attribute__((address_space(1))) void*)(g),
      (__attribute__((address_space(3))) void*)(l),
      16, 0, 0);
}

// ---------- conversion kernels ----------
__global__ void convert_combined(const float* __restrict__ x,
                                 const float* __restrict__ hl,
                                 const float* __restrict__ hr,
                                 short* __restrict__ out) {
  const int total  = B_ROWS * (KDIM / 8);
  const int stride = gridDim.x * blockDim.x;
  for (int i = blockIdx.x * blockDim.x + threadIdx.x; i < total; i += stride) {
    int row = i / (KDIM / 8);
    int col = (i - row * (KDIM / 8)) * 8;
    const float* src;
    if (col < 1024)      src = x  + (int64_t)row * 1024 + col;
    else if (col < 2048) src = hl + (int64_t)row * 1024 + (col - 1024);
    else                 src = hr + (int64_t)row * 1024 + (col - 2048);
    float4 v0 = ((const float4*)src)[0];
    float4 v1 = ((const float4*)src)[1];
    short8 r;
    r[0] = f2bf(v0.x); r[1] = f2bf(v0.y); r[2] = f2bf(v0.z); r[3] = f2bf(v0.w);
    r[4] = f2bf(v1.x); r[5] = f2bf(v1.y); r[6] = f2bf(v1.z); r[7] = f2bf(v1.w);
    *(short8*)(out + (int64_t)row * KDIM + col) = r;
  }
}

__global__ void convert_w(const float* __restrict__ Wf, short* __restrict__ out) {
  const int total  = NGATE * HID * (KDIM / 8);
  const int stride = gridDim.x * blockDim.x;
  for (int i = blockIdx.x * blockDim.x + threadIdx.x; i < total; i += stride) {
    int64_t e = (int64_t)i * 8;
    float4 v0 = ((const float4*)(Wf + e))[0];
    float4 v1 = ((const float4*)(Wf + e))[1];
    short8 r;
    r[0] = f2bf(v0.x); r[1] = f2bf(v0.y); r[2] = f2bf(v0.z); r[3] = f2bf(v0.w);
    r[4] = f2bf(v1.x); r[5] = f2bf(v1.y); r[6] = f2bf(v1.z); r[7] = f2bf(v1.w);
    *(short8*)(out + e) = r;
  }
}

// ---------- fused GEMM + LSTM-cell epilogue ----------
// LDS layout: row-PAIRS interleaved: [pairrow][8 slots x 16B]; slot s of
// pairrow p stored at s ^ (p&7) (source pre-swizzled, rule #21). Row r ->
// pairrow r>>1, its 4 k-slots at (r&1)*4 + khalf. ds_read_b128 worst case
// 2-way bank aliasing (free). Drift schedule (R5): stage t+1 at tile start,
// one vmcnt(0)+lgkmcnt(0)+barrier per tile; 2 blocks/CU overlap each other's
// drains. setprio(1) around the MFMA section (cross-block role diversity).
__global__ __launch_bounds__(512, 4) void lstm_gemm(
    const short* __restrict__ Abf,   // [8192][3072] bf16
    const short* __restrict__ Wbf,   // [5120][3072] bf16
    const float* __restrict__ bias,  // [5120]
    const float* __restrict__ c_left,
    const float* __restrict__ c_right,
    float* __restrict__ out) {       // h at 0, c at 8192*1024
  __shared__ short lds[2 * BUF_SH];  // 72 KiB
  char* const ldsc = (char*)lds;

  const int tid = threadIdx.x;
  const int w  = tid >> 6;     // 0..7
  const int l  = tid & 63;
  const int wm = w >> 2;       // 0..1
  const int wn = w & 3;        // 0..3
  const int lc = l & 15;
  const int khalf = l >> 4;    // 0..3

  // XCD-aware bijective swizzle (512 % 8 == 0)
  const int bid = blockIdx.x;
  const int wg  = (bid & 7) * 64 + (bid >> 3);
  const int m0  = (wg >> 4) * BM;
  const int j0  = (wg & 15) * 64;

  // ---- staging source offsets (elements into Abf/Wbf), pre-swizzled ----
  // One load = 8 pairrows (16 rows x 64B). lane l -> pairrow += l>>3,
  // LDS slot l&7; source slot s = (l&7) ^ (l>>3); source row parity s>>2,
  // source 16B chunk s&3.
  const int r8 = l >> 3;
  const int s_src = (l & 7) ^ r8;
  // A: wave w stages pairrows [w*16, w*16+16) as 2 loads of 8.
  u32 aoffA[2];
#pragma unroll
  for (int i = 0; i < 2; ++i) {
    int pl = w * 16 + i * 8 + r8;
    int row = m0 + 2 * pl + (s_src >> 2);
    aoffA[i] = (u32)row * KDIM + (s_src & 3) * 8;
  }
  // B: 20 loads; wave w takes n = w, 8+w, and 16+w (if w<4).
  // B-LDS row rb (0..319) -> W row: g=(rb%80)>>4, wn_r=rb/80, dj=rb&15.
  u32 aoffB[3];
#pragma unroll
  for (int i = 0; i < 3; ++i) {
    int n = w + i * 8;
    if (n < 20) {
      int pn = n * 8 + r8;
      int rb = 2 * pn + (s_src >> 2);
      int g  = (rb % 80) >> 4;
      int wn_r = rb / 80;
      int dj = rb & 15;
      aoffB[i] = (u32)(g * HID + j0 + wn_r * 16 + dj) * KDIM + (s_src & 3) * 8;
    } else aoffB[i] = 0;
  }

  // ---- ds_read byte addresses (buffer 0) ----
  // slot' = ((r&1)*4 + khalf) ^ (pairrow&7); pairrow&7 == (lc>>1)&7.
  const u32 slotp = (u32)((((lc & 1) * 4 + khalf) ^ ((lc >> 1) & 7)) * 16);
  // A frag m: pairrow = wm*64 + m*8 + (lc>>1)  -> +m*1024 bytes immediate
  u32 aAd = (u32)((wm * 64 + (lc >> 1)) * 128) + slotp;
  // B frag g: pairrow = wn*40 + g*8 + (lc>>1)  -> +g*1024 bytes immediate
  u32 bAd = (u32)(LDSA_SH * 2) + (u32)((wn * 40 + (lc >> 1)) * 128) + slotp;

  f32x4 acc[8][5];
  const f32x4 zero = {0.0f, 0.0f, 0.0f, 0.0f};
#pragma unroll
  for (int m = 0; m < 8; ++m)
#pragma unroll
    for (int n = 0; n < 5; ++n) acc[m][n] = zero;

  // ---- prologue: stage tile 0 into buffer 0 ----
#pragma unroll
  for (int i = 0; i < 2; ++i)
    async_copy16(Abf + aoffA[i], lds + w * 1024 + i * 512);
#pragma unroll
  for (int i = 0; i < 2; ++i)
    async_copy16(Wbf + aoffB[i], lds + LDSA_SH + (w + i * 8) * 512);
  if (w < 4)
    async_copy16(Wbf + aoffB[2], lds + LDSA_SH + (16 + w) * 512);
#pragma unroll
  for (int i = 0; i < 2; ++i) aoffA[i] += BK;
#pragma unroll
  for (int i = 0; i < 3; ++i) aoffB[i] += BK;
  asm volatile("s_waitcnt vmcnt(0)" ::: "memory");
  __builtin_amdgcn_s_barrier();

  int bufd = BUF_BYTES;
  for (int t = 0; t < NT; ++t) {
    // ---- stage t+1 into the other buffer ----
    if (t < NT - 1) {
      short* dA = lds + ((t + 1) & 1) * BUF_SH;
      short* dB = dA + LDSA_SH;
#pragma unroll
      for (int i = 0; i < 2; ++i)
        async_copy16(Abf + aoffA[i], dA + w * 1024 + i * 512);
#pragma unroll
      for (int i = 0; i < 2; ++i)
        async_copy16(Wbf + aoffB[i], dB + (w + i * 8) * 512);
      if (w < 4)
        async_copy16(Wbf + aoffB[2], dB + (16 + w) * 512);
#pragma unroll
      for (int i = 0; i < 2; ++i) aoffA[i] += BK;
#pragma unroll
      for (int i = 0; i < 3; ++i) aoffB[i] += BK;
    }

    // ---- compute: one K-step of 32 ----
    bf16x8 bfr[5];
#pragma unroll
    for (int g = 0; g < 5; ++g)
      bfr[g] = *(const bf16x8*)(ldsc + bAd + g * 1024);
    __builtin_amdgcn_s_setprio(1);
#pragma unroll
    for (int m = 0; m < 8; ++m) {
      bf16x8 af = *(const bf16x8*)(ldsc + aAd + m * 1024);
#pragma unroll
      for (int g = 0; g < 5; ++g)
        acc[m][g] = __builtin_amdgcn_mfma_f32_16x16x32_bf16(
            af, bfr[g], acc[m][g], 0, 0, 0);
    }
    __builtin_amdgcn_s_setprio(0);

    // ---- tile boundary: staging landed, my reads drained, then sync ----
    asm volatile("s_waitcnt vmcnt(0) lgkmcnt(0)" ::: "memory");
    __builtin_amdgcn_s_barrier();

    aAd += bufd; bAd += bufd;
    bufd = -bufd;
  }

  // ---- epilogue: 5 gates for (row, j) all live in this lane ----
  const int j = j0 + wn * 16 + lc;
  float bi[5];
#pragma unroll
  for (int g = 0; g < 5; ++g) bi[g] = bias[g * HID + j];
#pragma unroll
  for (int m = 0; m < 8; ++m) {
#pragma unroll
    for (int r = 0; r < 4; ++r) {
      const int row = m0 + wm * 128 + m * 16 + khalf * 4 + r;
      const int off = row * HID + j;
      float iv  = sigf(acc[m][0][r] + bi[0]);
      float flv = sigf(acc[m][1][r] + bi[1]);
      float frv = sigf(acc[m][2][r] + bi[2]);
      float ov  = sigf(acc[m][3][r] + bi[3]);
      float uv  = tanhf(acc[m][4][r] + bi[4]);
      float cv  = iv * uv + flv * c_left[off] + frv * c_right[off];
      out[off] = ov * tanhf(cv);
      out[B_ROWS * HID + off] = cv;
    }
  }
}

// ---------- fp32 fallback (only if ws too small) ----------
__global__ void lstm_fallback(const float* __restrict__ x, const float* __restrict__ hl,
                              const float* __restrict__ hr, const float* __restrict__ cl,
                              const float* __restrict__ cr, const float* __restrict__ W,
                              const float* __restrict__ b, float* __restrict__ out) {
  int64_t idx = (int64_t)blockIdx.x * blockDim.x + threadIdx.x;
  if (idx >= (int64_t)B_ROWS * HID) return;
  int bi = (int)(idx >> 10);
  int j  = (int)(idx & 1023);
  float acc[5];
#pragma unroll
  for (int g = 0; g < 5; ++g) acc[g] = b[g * HID + j];
  const float* segs[3] = {x + (int64_t)bi * 1024, hl + (int64_t)bi * 1024,
                          hr + (int64_t)bi * 1024};
  for (int s = 0; s < 3; ++s) {
    const float4* v = (const float4*)segs[s];
    for (int k4 = 0; k4 < 256; ++k4) {
      float4 a = v[k4];
#pragma unroll
      for (int g = 0; g < 5; ++g) {
        const float4 wv = *(const float4*)(W + (int64_t)(g * HID + j) * KDIM + s * 1024 + k4 * 4);
        acc[g] += a.x * wv.x + a.y * wv.y + a.z * wv.z + a.w * wv.w;
      }
    }
  }
  float iv = sigf(acc[0]), fl = sigf(acc[1]), fr = sigf(acc[2]), ov = sigf(acc[3]);
  float uv = tanhf(acc[4]);
  float cv = iv * uv + fl * cl[idx] + fr * cr[idx];
  out[idx] = ov * tanhf(cv);
  out[(int64_t)B_ROWS * HID + idx] = cv;
}

// ---------- host ----------
extern "C" void kernel_launch(void* const* d_in, const int* in_sizes, int n_in,
                              void* d_out, int out_size, void* d_ws, size_t ws_size,
                              hipStream_t stream) {
  const float* x  = (const float*)d_in[0];
  const float* hl = (const float*)d_in[1];
  const float* cl = (const float*)d_in[2];
  const float* hr = (const float*)d_in[3];
  const float* cr = (const float*)d_in[4];
  const float* W  = (const float*)d_in[5];
  const float* b  = (const float*)d_in[6];
  float* out = (float*)d_out;

  const size_t needA = (size_t)B_ROWS * KDIM * sizeof(short);      // 48 MiB
  const size_t needW = (size_t)NGATE * HID * KDIM * sizeof(short); // 30 MiB

  if (ws_size >= needA + needW) {
    short* Abf = (short*)d_ws;
    short* Wbf = (short*)((char*)d_ws + needA);
    convert_combined<<<2048, 256, 0, stream>>>(x, hl, hr, Abf);
    convert_w<<<2048, 256, 0, stream>>>(W, Wbf);
    lstm_gemm<<<512, 512, 0, stream>>>(Abf, Wbf, b, cl, cr, out);
  } else {
    lstm_fallback<<<(B_ROWS * HID) / 256, 256, 0, stream>>>(x, hl, hr, cl, cr, W, b, out);
  }
}

// Round 8
// 323.695 us; speedup vs baseline: 6.7934x; 6.7934x over previous
//
#include <hip/hip_runtime.h>
#include <stdint.h>

typedef unsigned int u32;
typedef short short8 __attribute__((ext_vector_type(8)));
typedef short bf16x8 __attribute__((ext_vector_type(8)));
typedef float f32x4  __attribute__((ext_vector_type(4)));

#define B_ROWS 8192
#define HID    1024
#define KDIM   3072
#define NGATE  5

// GEMM tile: 256 batch rows x (5 gates x 64 hidden) per block, 8 waves 2Mx4N,
// per-wave output 128x80 (8 M-frags x 5 N-frags; N-frag == gate index).
#define BM 256
#define BN 320
#define BK 64
#define NT (KDIM / BK)               // 48
#define LDSA_SH (BM * BK)            // 16384 shorts
#define LDSB_SH (BN * BK)            // 20480 shorts
#define BUF_SH  (LDSA_SH + LDSB_SH)  // 36864 shorts = 72 KiB
#define BUF_BYTES (BUF_SH * 2)       // 73728

// ---------- helpers ----------
__device__ __forceinline__ short f2bf(float f) {
  u32 u = __builtin_bit_cast(u32, f);
  u += 0x7FFFu + ((u >> 16) & 1u);   // round-to-nearest-even
  return (short)(u >> 16);
}

__device__ __forceinline__ float sigf(float v) { return 1.0f / (1.0f + __expf(-v)); }

__device__ __forceinline__ void async_copy16(const void* g, void* l) {
  __builtin_amdgcn_global_load_lds(
      (__attribute__((address_space(1))) void*)(g),
      (__attribute__((address_space(3))) void*)(l),
      16, 0, 0);
}

// ---------- conversion kernels ----------
__global__ void convert_combined(const float* __restrict__ x,
                                 const float* __restrict__ hl,
                                 const float* __restrict__ hr,
                                 short* __restrict__ out) {
  const int total  = B_ROWS * (KDIM / 8);
  const int stride = gridDim.x * blockDim.x;
  for (int i = blockIdx.x * blockDim.x + threadIdx.x; i < total; i += stride) {
    int row = i / (KDIM / 8);
    int col = (i - row * (KDIM / 8)) * 8;
    const float* src;
    if (col < 1024)      src = x  + (int64_t)row * 1024 + col;
    else if (col < 2048) src = hl + (int64_t)row * 1024 + (col - 1024);
    else                 src = hr + (int64_t)row * 1024 + (col - 2048);
    float4 v0 = ((const float4*)src)[0];
    float4 v1 = ((const float4*)src)[1];
    short8 r;
    r[0] = f2bf(v0.x); r[1] = f2bf(v0.y); r[2] = f2bf(v0.z); r[3] = f2bf(v0.w);
    r[4] = f2bf(v1.x); r[5] = f2bf(v1.y); r[6] = f2bf(v1.z); r[7] = f2bf(v1.w);
    *(short8*)(out + (int64_t)row * KDIM + col) = r;
  }
}

__global__ void convert_w(const float* __restrict__ Wf, short* __restrict__ out) {
  const int total  = NGATE * HID * (KDIM / 8);
  const int stride = gridDim.x * blockDim.x;
  for (int i = blockIdx.x * blockDim.x + threadIdx.x; i < total; i += stride) {
    int64_t e = (int64_t)i * 8;
    float4 v0 = ((const float4*)(Wf + e))[0];
    float4 v1 = ((const float4*)(Wf + e))[1];
    short8 r;
    r[0] = f2bf(v0.x); r[1] = f2bf(v0.y); r[2] = f2bf(v0.z); r[3] = f2bf(v0.w);
    r[4] = f2bf(v1.x); r[5] = f2bf(v1.y); r[6] = f2bf(v1.z); r[7] = f2bf(v1.w);
    *(short8*)(out + e) = r;
  }
}

// ---------- fused GEMM + LSTM-cell epilogue (m201-faithful schedule) ----------
// Per phase p: {ds_read phase frags; issue this phase's staging for tile t+2
// into slices of buf[t&1] that died last phase; s_barrier; lgkmcnt(0);
// setprio(1) 20xMFMA setprio(0); [p3: counted vmcnt]; s_barrier}.
// Slice deaths: B(t) after p0 (read once into regs); A slice s after phase s.
// Staging: B(t+2) at p1 (all waves, 5 loads); A(t+2) slice s at phase s+1 by
// wave-group s (4 loads), s=3 wrapping to NEXT tile's p0 (stages A(t+1)).
// Tile-end wait: vmcnt(9) (wsel3: vmcnt(5)) guarantees tile t+1 landed while
// tile t+2's loads stay in flight; vmcnt(0) only at t==NT-2.
__global__ __launch_bounds__(512, 2) void lstm_gemm(
    const short* __restrict__ Abf,   // [8192][3072] bf16
    const short* __restrict__ Wbf,   // [5120][3072] bf16
    const float* __restrict__ bias,  // [5120]
    const float* __restrict__ c_left,
    const float* __restrict__ c_right,
    float* __restrict__ out) {       // h at 0, c at 8192*1024
  __shared__ short lds[2 * BUF_SH];  // 144 KiB
  char* const ldsc = (char*)lds;

  const int tid = threadIdx.x;
  const int w  = tid >> 6;     // 0..7
  const int l  = tid & 63;
  const int wm = w >> 2;       // 0..1
  const int wn = w & 3;        // 0..3
  const int wsel = w & 3;      // A-slice this wave stages
  const int lc = l & 15;
  const int khalf = l >> 4;    // 0..3

  // XCD-aware bijective swizzle (512 % 8 == 0)
  const int bid = blockIdx.x;
  const int wg  = (bid & 7) * 64 + (bid >> 3);
  const int m0  = (wg >> 4) * BM;
  const int j0  = (wg & 15) * 64;

  // staging source offsets: per wave-load 8 rows x 128B; lane l -> row l>>3,
  // 16B slot (l&7) XOR row (pre-swizzled source, rule #21)
  const int r8 = l >> 3;
  const int sl = (l & 7) ^ r8;
  u32 aoff[4], boff[5];
#pragma unroll
  for (int i = 0; i < 4; ++i)
    aoff[i] = (u32)(m0 + (w * 4 + i) * 8 + r8) * KDIM + sl * 8;
#pragma unroll
  for (int i = 0; i < 5; ++i) {
    int rb = (w * 5 + i) * 8 + r8;                 // 0..319
    int g  = (rb % 80) >> 4;
    int dj = (rb / 80) * 16 + (rb & 15);
    boff[i] = (u32)(g * HID + j0 + dj) * KDIM + sl * 8;
  }
  // staging destination toggles (byte offset of the buffer for the NEXT stage)
  u32 stA = 0, stB = 0;

#define STAGE_A()                                                          \
  do {                                                                     \
    short* dA_ = (short*)(ldsc + stA);                                     \
    _Pragma("unroll")                                                      \
    for (int i_ = 0; i_ < 4; ++i_)                                         \
      async_copy16(Abf + aoff[i_], dA_ + (w * 4 + i_) * 512);              \
    _Pragma("unroll")                                                      \
    for (int i_ = 0; i_ < 4; ++i_) aoff[i_] += BK;                         \
    stA ^= BUF_BYTES;                                                      \
  } while (0)

#define STAGE_B()                                                          \
  do {                                                                     \
    short* dB_ = (short*)(ldsc + stB) + LDSA_SH;                           \
    _Pragma("unroll")                                                      \
    for (int i_ = 0; i_ < 5; ++i_)                                         \
      async_copy16(Wbf + boff[i_], dB_ + (w * 5 + i_) * 512);              \
    _Pragma("unroll")                                                      \
    for (int i_ = 0; i_ < 5; ++i_) boff[i_] += BK;                         \
    stB ^= BUF_BYTES;                                                      \
  } while (0)

  // ds_read byte addresses (buffer 0); row&7 == lc&7 since rows are 16k+lc
  const u32 sw0 = (u32)(((khalf    ) ^ (lc & 7)) * 16);
  const u32 sw1 = (u32)(((khalf + 4) ^ (lc & 7)) * 16);
  u32 aAd0 = (u32)((wm * 128 + lc) * 128) + sw0;
  u32 aAd1 = (u32)((wm * 128 + lc) * 128) + sw1;
  u32 bAd0 = (u32)(LDSA_SH * 2) + (u32)((wn * 80 + lc) * 128) + sw0;
  u32 bAd1 = (u32)(LDSA_SH * 2) + (u32)((wn * 80 + lc) * 128) + sw1;

  f32x4 acc[8][5];
  const f32x4 zero = {0.0f, 0.0f, 0.0f, 0.0f};
#pragma unroll
  for (int m = 0; m < 8; ++m)
#pragma unroll
    for (int n = 0; n < 5; ++n) acc[m][n] = zero;

  // ---- prologue: stage tiles 0 and 1 fully; wait only for tile 0 ----
  STAGE_A(); STAGE_B();   // tile 0 -> buf0
  STAGE_A(); STAGE_B();   // tile 1 -> buf1
  asm volatile("s_waitcnt vmcnt(9)" ::: "memory");
  __builtin_amdgcn_s_barrier();

  int bufd = BUF_BYTES;
  for (int t = 0; t < NT; ++t) {
    const bool canP = (t <= NT - 3);   // t+2 exists
    bf16x8 bfr[5][2];
#pragma unroll
    for (int p = 0; p < 4; ++p) {
      // ---- read step: this phase's fragments ----
      if (p == 0) {
#pragma unroll
        for (int nf = 0; nf < 5; ++nf) {
          bfr[nf][0] = *(const bf16x8*)(ldsc + bAd0 + nf * 2048);
          bfr[nf][1] = *(const bf16x8*)(ldsc + bAd1 + nf * 2048);
        }
      }
      bf16x8 af[2][2];
#pragma unroll
      for (int mf = 0; mf < 2; ++mf) {
        af[mf][0] = *(const bf16x8*)(ldsc + aAd0 + (p * 32 + mf * 16) * 128);
        af[mf][1] = *(const bf16x8*)(ldsc + aAd1 + (p * 32 + mf * 16) * 128);
      }
      // ---- stage step (before the barrier: issues overlap the sync) ----
      if (p == 0) {
        if (wsel == 3 && t >= 1 && t <= NT - 2) STAGE_A();   // A(t+1) slice 3
      } else if (p == 1) {
        if (canP) STAGE_B();                                  // B(t+2)
        if (wsel == 0 && canP) STAGE_A();                     // A(t+2) slice 0
      } else if (p == 2) {
        if (wsel == 1 && canP) STAGE_A();                     // A(t+2) slice 1
      } else {
        if (wsel == 2 && canP) STAGE_A();                     // A(t+2) slice 2
      }
      __builtin_amdgcn_s_barrier();
      asm volatile("s_waitcnt lgkmcnt(0)" ::: "memory");
      __builtin_amdgcn_s_setprio(1);
#pragma unroll
      for (int mf = 0; mf < 2; ++mf)
#pragma unroll
        for (int nf = 0; nf < 5; ++nf)
#pragma unroll
          for (int kk = 0; kk < 2; ++kk)
            acc[p * 2 + mf][nf] = __builtin_amdgcn_mfma_f32_16x16x32_bf16(
                af[mf][kk], bfr[nf][kk], acc[p * 2 + mf][nf], 0, 0, 0);
      __builtin_amdgcn_s_setprio(0);
      if (p == 3) {
        // counted tile-end wait: tile t+1 landed, tile t+2 stays in flight
        if (t < NT - 2) {
          if (wsel == 3) asm volatile("s_waitcnt vmcnt(5)" ::: "memory");
          else           asm volatile("s_waitcnt vmcnt(9)" ::: "memory");
        } else if (t == NT - 2) {
          asm volatile("s_waitcnt vmcnt(0)" ::: "memory");
        }
      }
      __builtin_amdgcn_s_barrier();
    }
    aAd0 += bufd; aAd1 += bufd; bAd0 += bufd; bAd1 += bufd;
    bufd = -bufd;
  }

  // ---- epilogue: 5 gates for (row, j) all live in this lane ----
  const int j = j0 + wn * 16 + lc;
  float bi[5];
#pragma unroll
  for (int g = 0; g < 5; ++g) bi[g] = bias[g * HID + j];
#pragma unroll
  for (int m = 0; m < 8; ++m) {
#pragma unroll
    for (int r = 0; r < 4; ++r) {
      const int row = m0 + wm * 128 + m * 16 + khalf * 4 + r;
      const int off = row * HID + j;
      float iv  = sigf(acc[m][0][r] + bi[0]);
      float flv = sigf(acc[m][1][r] + bi[1]);
      float frv = sigf(acc[m][2][r] + bi[2]);
      float ov  = sigf(acc[m][3][r] + bi[3]);
      float uv  = tanhf(acc[m][4][r] + bi[4]);
      float cv  = iv * uv + flv * c_left[off] + frv * c_right[off];
      out[off] = ov * tanhf(cv);
      out[B_ROWS * HID + off] = cv;
    }
  }
}

// ---------- fp32 fallback (only if ws too small) ----------
__global__ void lstm_fallback(const float* __restrict__ x, const float* __restrict__ hl,
                              const float* __restrict__ hr, const float* __restrict__ cl,
                              const float* __restrict__ cr, const float* __restrict__ W,
                              const float* __restrict__ b, float* __restrict__ out) {
  int64_t idx = (int64_t)blockIdx.x * blockDim.x + threadIdx.x;
  if (idx >= (int64_t)B_ROWS * HID) return;
  int bi = (int)(idx >> 10);
  int j  = (int)(idx & 1023);
  float acc[5];
#pragma unroll
  for (int g = 0; g < 5; ++g) acc[g] = b[g * HID + j];
  const float* segs[3] = {x + (int64_t)bi * 1024, hl + (int64_t)bi * 1024,
                          hr + (int64_t)bi * 1024};
  for (int s = 0; s < 3; ++s) {
    const float4* v = (const float4*)segs[s];
    for (int k4 = 0; k4 < 256; ++k4) {
      float4 a = v[k4];
#pragma unroll
      for (int g = 0; g < 5; ++g) {
        const float4 wv = *(const float4*)(W + (int64_t)(g * HID + j) * KDIM + s * 1024 + k4 * 4);
        acc[g] += a.x * wv.x + a.y * wv.y + a.z * wv.z + a.w * wv.w;
      }
    }
  }
  float iv = sigf(acc[0]), fl = sigf(acc[1]), fr = sigf(acc[2]), ov = sigf(acc[3]);
  float uv = tanhf(acc[4]);
  float cv = iv * uv + fl * cl[idx] + fr * cr[idx];
  out[idx] = ov * tanhf(cv);
  out[(int64_t)B_ROWS * HID + idx] = cv;
}

// ---------- host ----------
extern "C" void kernel_launch(void* const* d_in, const int* in_sizes, int n_in,
                              void* d_out, int out_size, void* d_ws, size_t ws_size,
                              hipStream_t stream) {
  const float* x  = (const float*)d_in[0];
  const float* hl = (const float*)d_in[1];
  const float* cl = (const float*)d_in[2];
  const float* hr = (const float*)d_in[3];
  const float* cr = (const float*)d_in[4];
  const float* W  = (const float*)d_in[5];
  const float* b  = (const float*)d_in[6];
  float* out = (float*)d_out;

  const size_t needA = (size_t)B_ROWS * KDIM * sizeof(short);      // 48 MiB
  const size_t needW = (size_t)NGATE * HID * KDIM * sizeof(short); // 30 MiB

  if (ws_size >= needA + needW) {
    short* Abf = (short*)d_ws;
    short* Wbf = (short*)((char*)d_ws + needA);
    convert_combined<<<2048, 256, 0, stream>>>(x, hl, hr, Abf);
    convert_w<<<2048, 256, 0, stream>>>(W, Wbf);
    lstm_gemm<<<512, 512, 0, stream>>>(Abf, Wbf, b, cl, cr, out);
  } else {
    lstm_fallback<<<(B_ROWS * HID) / 256, 256, 0, stream>>>(x, hl, hr, cl, cr, W, b, out);
  }
}